// Round 9
// baseline (313.665 us; speedup 1.0000x reference)
//
#include <hip/hip_runtime.h>
#include <hip/hip_bf16.h>
#include <cstdint>
#include <cstddef>

// B=2, S=4096, HID=512, H=8, D_K=64.
// cvt_w(weights only; scale log2e/ln64 folded into Wq) -> proj_qk (Q,K as
// [kM][512], f32 x converted in-register) + proj_v (TRANSPOSED gemm:
// V^T = Wv @ X^T -> coalesced [bh][d][s] stores via LDS transpose) ->
// flash attention v7 (unchanged from R8) -> output proj (f32 out).

namespace {

constexpr int kB = 2, kS = 4096, kHid = 512, kH = 8, kDk = 64;
constexpr int kBH = kB * kH;   // 16
constexpr int kM = kB * kS;    // 8192

typedef __attribute__((ext_vector_type(8))) short short8;
typedef __attribute__((ext_vector_type(4))) float floatx4;
typedef __attribute__((ext_vector_type(4))) unsigned int uint4v;
typedef unsigned short u16;

__device__ __forceinline__ u16 bf16rne(float f) {
    uint32_t u = __float_as_uint(f);
    u += 0x7fffu + ((u >> 16) & 1u);
    return (u16)(u >> 16);
}
__device__ __forceinline__ uint32_t pk2(float lo, float hi) {
#if __has_builtin(__builtin_amdgcn_cvt_pk_bf16_f32)
    typedef __attribute__((ext_vector_type(2))) __bf16 bf2;
    bf2 h = __builtin_amdgcn_cvt_pk_bf16_f32(lo, hi);
    return __builtin_bit_cast(uint32_t, h);
#else
    return ((uint32_t)bf16rne(hi) << 16) | (uint32_t)bf16rne(lo);
#endif
}
__device__ __forceinline__ short8 pk8(float4 f0, float4 f1) {
    uint4v u;
    u[0] = pk2(f0.x, f0.y); u[1] = pk2(f0.z, f0.w);
    u[2] = pk2(f1.x, f1.y); u[3] = pk2(f1.z, f1.w);
    return __builtin_bit_cast(short8, u);
}
__device__ __forceinline__ float fexp2(float x) {
#if __has_builtin(__builtin_amdgcn_exp2f)
    return __builtin_amdgcn_exp2f(x);
#else
    return exp2f(x);
#endif
}

// ---- weights f32->bf16; Wq gets scale = log2(e)/ln(64) ---------------------
__global__ __launch_bounds__(256) void cvt_w(const float* __restrict__ w0,
    const float* __restrict__ w1, const float* __restrict__ w2,
    const float* __restrict__ w3, u16* __restrict__ wall) {
    int z = blockIdx.x >> 8;
    size_t i = (size_t)(blockIdx.x & 255) * 256 + threadIdx.x;
    const float* src = z == 0 ? w0 : (z == 1 ? w1 : (z == 2 ? w2 : w3));
    float sc = (z == 0)
        ? (float)(1.4426950408889634 / (6.0 * 0.6931471805599453))  // log2e/ln64
        : 1.0f;
    float4 f = ((const float4*)src)[i];
    ushort4 o;
    o.x = bf16rne(f.x * sc); o.y = bf16rne(f.y * sc);
    o.z = bf16rne(f.z * sc); o.w = bf16rne(f.w * sc);
    ((ushort4*)(wall + (size_t)z * kHid * kHid))[i] = o;
}

// ---- mask -> float bias (0 or -1e30) ---------------------------------------
__global__ __launch_bounds__(256) void cvt_mask(const int* __restrict__ mask,
    float* __restrict__ fb) {
    int i = blockIdx.x * 256 + threadIdx.x;
    fb[i] = mask[i] ? 0.0f : -1e30f;
}

// ---- Q/K projection: out = x @ W^T; x read as f32, cvt in-register ---------
// grid (4, 64, 2); block 128x128 tile, wave 64x64. dst [kM][512].
__global__ __launch_bounds__(256, 3) void proj_qk(const float* __restrict__ xq,
    const float* __restrict__ xk, const u16* __restrict__ wall,
    u16* __restrict__ qp, u16* __restrict__ kp) {
    __shared__ float smt[4][16][68];
    const int z = blockIdx.z;
    const float* x = z ? xk : xq;
    const u16* w = wall + (size_t)z * kHid * kHid;
    u16* dst = z ? kp : qp;
    const int wv = threadIdx.x >> 6, lane = threadIdx.x & 63;
    const int quad = lane >> 4, l16 = lane & 15;
    const int mb = blockIdx.y * 128 + (wv >> 1) * 64;
    const int nb = blockIdx.x * 128 + (wv & 1) * 64;
    floatx4 acc[4][4] = {};
    const float* xr = x + (size_t)(mb + l16) * kHid + quad * 8;
    const u16* wr = w + (size_t)(nb + l16) * kHid + quad * 8;
    for (int k0 = 0; k0 < kHid; k0 += 32) {
        short8 a[4], bt[4];
#pragma unroll
        for (int i = 0; i < 4; i++) {
            const float* p = xr + (size_t)i * 16 * kHid + k0;
            a[i] = pk8(*(const float4*)p, *(const float4*)(p + 4));
        }
#pragma unroll
        for (int t = 0; t < 4; t++)
            bt[t] = *(const short8*)(wr + (size_t)t * 16 * kHid + k0);
#pragma unroll
        for (int i = 0; i < 4; i++)
#pragma unroll
        for (int t = 0; t < 4; t++)
            acc[i][t] = __builtin_amdgcn_mfma_f32_16x16x32_bf16(a[i], bt[t], acc[i][t], 0, 0, 0);
    }
    // LDS transpose -> coalesced 16B stores
    const int row16 = lane >> 2, cseg = (lane & 3) * 16;
#pragma unroll
    for (int i = 0; i < 4; i++) {
#pragma unroll
        for (int t = 0; t < 4; t++)
#pragma unroll
        for (int r = 0; r < 4; r++)
            smt[wv][quad * 4 + r][t * 16 + l16] = acc[i][t][r];
        __builtin_amdgcn_wave_barrier();
        const float* rp = &smt[wv][row16][cseg];
        float4 f0 = *(const float4*)(rp);
        float4 f1 = *(const float4*)(rp + 4);
        float4 f2 = *(const float4*)(rp + 8);
        float4 f3 = *(const float4*)(rp + 12);
        uint4 o0, o1;
        o0.x = pk2(f0.x, f0.y); o0.y = pk2(f0.z, f0.w);
        o0.z = pk2(f1.x, f1.y); o0.w = pk2(f1.z, f1.w);
        o1.x = pk2(f2.x, f2.y); o1.y = pk2(f2.z, f2.w);
        o1.z = pk2(f3.x, f3.y); o1.w = pk2(f3.z, f3.w);
        u16* dp = dst + (size_t)(mb + i * 16 + row16) * kHid + nb + cseg;
        *(uint4*)dp = o0;
        *(uint4*)(dp + 8) = o1;
        __builtin_amdgcn_wave_barrier();
    }
}

// ---- V projection, transposed: V^T = Wv @ X^T ------------------------------
// grid (64, 4); M=512 (m=h*64+d), N=8192 (n=b*4096+s). A=Wv bf16, B=x_v f32.
// dst vt[b][m][4096]: same LDS-transpose epilogue -> 16B stores along s.
__global__ __launch_bounds__(256, 3) void proj_v(const float* __restrict__ xv,
    const u16* __restrict__ wall, u16* __restrict__ vt) {
    __shared__ float smt[4][16][68];
    const u16* w = wall + (size_t)2 * kHid * kHid;
    const int wv = threadIdx.x >> 6, lane = threadIdx.x & 63;
    const int quad = lane >> 4, l16 = lane & 15;
    const int mb = blockIdx.y * 128 + (wv >> 1) * 64;     // m = h*64+d
    const int nbg = blockIdx.x * 128 + (wv & 1) * 64;     // n = b*4096+s
    const int b = nbg >> 12, s0 = nbg & (kS - 1);
    floatx4 acc[4][4] = {};
    const u16* ar = w + (size_t)(mb + l16) * kHid + quad * 8;
    const float* br = xv + (size_t)(nbg + l16) * kHid + quad * 8;
    for (int k0 = 0; k0 < kHid; k0 += 32) {
        short8 a[4], bt[4];
#pragma unroll
        for (int i = 0; i < 4; i++)
            a[i] = *(const short8*)(ar + (size_t)i * 16 * kHid + k0);
#pragma unroll
        for (int t = 0; t < 4; t++) {
            const float* p = br + (size_t)t * 16 * kHid + k0;
            bt[t] = pk8(*(const float4*)p, *(const float4*)(p + 4));
        }
#pragma unroll
        for (int i = 0; i < 4; i++)
#pragma unroll
        for (int t = 0; t < 4; t++)
            acc[i][t] = __builtin_amdgcn_mfma_f32_16x16x32_bf16(a[i], bt[t], acc[i][t], 0, 0, 0);
    }
    const int row16 = lane >> 2, cseg = (lane & 3) * 16;
    u16* dstb = vt + (size_t)b * kHid * kS;
#pragma unroll
    for (int i = 0; i < 4; i++) {
#pragma unroll
        for (int t = 0; t < 4; t++)
#pragma unroll
        for (int r = 0; r < 4; r++)
            smt[wv][quad * 4 + r][t * 16 + l16] = acc[i][t][r];
        __builtin_amdgcn_wave_barrier();
        const float* rp = &smt[wv][row16][cseg];
        float4 f0 = *(const float4*)(rp);
        float4 f1 = *(const float4*)(rp + 4);
        float4 f2 = *(const float4*)(rp + 8);
        float4 f3 = *(const float4*)(rp + 12);
        uint4 o0, o1;
        o0.x = pk2(f0.x, f0.y); o0.y = pk2(f0.z, f0.w);
        o0.z = pk2(f1.x, f1.y); o0.w = pk2(f1.z, f1.w);
        o1.x = pk2(f2.x, f2.y); o1.y = pk2(f2.z, f2.w);
        o1.z = pk2(f3.x, f3.y); o1.w = pk2(f3.z, f3.w);
        u16* dp = dstb + (size_t)(mb + i * 16 + row16) * kS + s0 + cseg;
        *(uint4*)dp = o0;
        *(uint4*)(dp + 8) = o1;
        __builtin_amdgcn_wave_barrier();
    }
}

// ---- flash attention v7 (unchanged from R8) --------------------------------
__global__ __launch_bounds__(256, 2) void attn(const u16* __restrict__ qp,
    const u16* __restrict__ kp, const u16* __restrict__ vt,
    const float* __restrict__ fbias, u16* __restrict__ xo) {
    union SmT {
        struct { u16 K[2][64][64]; u16 V[2][64][64]; u16 P[4][32][72]; } s;  // 51200 B
        float ep[4][32][68];                                                 // 34816 B
    };
    __shared__ __align__(16) SmT sm;
    const int tid = threadIdx.x;
    const int wv = tid >> 6, lane = tid & 63;
    const int quad = lane >> 4, l16 = lane & 15;
    const int bh = blockIdx.y, b = bh >> 3, h = bh & 7;
    const int q0 = blockIdx.x * 128 + wv * 32;
    const u16* Qb = qp + (size_t)b * kS * kHid + h * 64;   // [s][512] + h*64
    const u16* Kb = kp + (size_t)b * kS * kHid + h * 64;
    const u16* Vb = vt + (size_t)bh * kDk * kS;            // [d][s]
    const float* fm = fbias + b * kS;

    short8 qf[2][2];
#pragma unroll
    for (int qt = 0; qt < 2; qt++)
#pragma unroll
    for (int hh = 0; hh < 2; hh++)
        qf[qt][hh] = *(const short8*)(Qb + (size_t)(q0 + qt * 16 + l16) * kHid + hh * 32 + quad * 8);

    floatx4 O[2][4] = {};
    float rs[2] = {0.0f, 0.0f};

    const int srow = tid >> 3;                    // 0..31
    const int sc   = (tid & 7) * 8;               // logical col (u16)
    const int pc   = ((tid & 7) ^ (srow & 7)) * 8; // physical col (u16)
    const int cA = (quad ^ (l16 & 7)) * 8;

    short8 rk[2], rv[2];
    rk[0] = *(const short8*)(Kb + (size_t)srow * kHid + sc);
    rk[1] = *(const short8*)(Kb + (size_t)(srow + 32) * kHid + sc);
    rv[0] = *(const short8*)(Vb + (size_t)srow * kS + sc);
    rv[1] = *(const short8*)(Vb + (size_t)(srow + 32) * kS + sc);
    *(short8*)&sm.s.K[0][srow][pc]      = rk[0];
    *(short8*)&sm.s.K[0][srow + 32][pc] = rk[1];
    *(short8*)&sm.s.V[0][srow][pc]      = rv[0];
    *(short8*)&sm.s.V[0][srow + 32][pc] = rv[1];
    rk[0] = *(const short8*)(Kb + (size_t)(64 + srow) * kHid + sc);
    rk[1] = *(const short8*)(Kb + (size_t)(64 + srow + 32) * kHid + sc);
    rv[0] = *(const short8*)(Vb + (size_t)srow * kS + 64 + sc);
    rv[1] = *(const short8*)(Vb + (size_t)(srow + 32) * kS + 64 + sc);
    __syncthreads();

    for (int it = 0; it < 64; ++it) {
        const int p = it & 1;
        const int kt = it * 64;
        *(short8*)&sm.s.K[1 - p][srow][pc]      = rk[0];
        *(short8*)&sm.s.K[1 - p][srow + 32][pc] = rk[1];
        *(short8*)&sm.s.V[1 - p][srow][pc]      = rv[0];
        *(short8*)&sm.s.V[1 - p][srow + 32][pc] = rv[1];
        {
            const int kt2 = ((it + 2) & 63) * 64;
            rk[0] = *(const short8*)(Kb + (size_t)(kt2 + srow) * kHid + sc);
            rk[1] = *(const short8*)(Kb + (size_t)(kt2 + srow + 32) * kHid + sc);
            rv[0] = *(const short8*)(Vb + (size_t)srow * kS + kt2 + sc);
            rv[1] = *(const short8*)(Vb + (size_t)(srow + 32) * kS + kt2 + sc);
        }
        float4 fb[4];
#pragma unroll
        for (int t = 0; t < 4; t++)
            fb[t] = *(const float4*)(fm + kt + t * 16 + quad * 4);
        short8 kf[4][2], vf[4][2];
#pragma unroll
        for (int t = 0; t < 4; t++) {
            kf[t][0] = *(const short8*)&sm.s.K[p][t * 16 + l16][cA];
            kf[t][1] = *(const short8*)&sm.s.K[p][t * 16 + l16][cA ^ 32];
            vf[t][0] = *(const short8*)&sm.s.V[p][t * 16 + l16][cA];
            vf[t][1] = *(const short8*)&sm.s.V[p][t * 16 + l16][cA ^ 32];
        }
#pragma unroll
        for (int qt = 0; qt < 2; qt++) {
            floatx4 st[4];
#pragma unroll
            for (int t = 0; t < 4; t++) {
                floatx4 z = {fb[t].x, fb[t].y, fb[t].z, fb[t].w};
                z = __builtin_amdgcn_mfma_f32_16x16x32_bf16(kf[t][0], qf[qt][0], z, 0, 0, 0);
                st[t] = __builtin_amdgcn_mfma_f32_16x16x32_bf16(kf[t][1], qf[qt][1], z, 0, 0, 0);
            }
            u16* prow = &sm.s.P[wv][qt * 16 + l16][0];
            float sum = 0.0f;
#pragma unroll
            for (int t = 0; t < 4; t++) {
                float p0 = fexp2(st[t][0]);
                float p1 = fexp2(st[t][1]);
                float p2 = fexp2(st[t][2]);
                float p3 = fexp2(st[t][3]);
                sum += (p0 + p1) + (p2 + p3);
                uint2 w2; w2.x = pk2(p0, p1); w2.y = pk2(p2, p3);
                *(uint2*)(prow + t * 16 + quad * 4) = w2;
            }
            rs[qt] += sum;
        }
        __builtin_amdgcn_wave_barrier();
#pragma unroll
        for (int qt = 0; qt < 2; qt++) {
            short8 ap0 = *(const short8*)&sm.s.P[wv][qt * 16 + l16][quad * 8];
            short8 ap1 = *(const short8*)&sm.s.P[wv][qt * 16 + l16][32 + quad * 8];
#pragma unroll
            for (int td = 0; td < 4; td++) {
                O[qt][td] = __builtin_amdgcn_mfma_f32_16x16x32_bf16(vf[td][0], ap0, O[qt][td], 0, 0, 0);
                O[qt][td] = __builtin_amdgcn_mfma_f32_16x16x32_bf16(vf[td][1], ap1, O[qt][td], 0, 0, 0);
            }
        }
        __syncthreads();
    }

    float inv[2];
#pragma unroll
    for (int qt = 0; qt < 2; qt++) {
        float r = rs[qt];
        r += __shfl_xor(r, 16);
        r += __shfl_xor(r, 32);
        inv[qt] = 1.0f / r;
    }
#pragma unroll
    for (int qt = 0; qt < 2; qt++)
#pragma unroll
    for (int td = 0; td < 4; td++) {
        floatx4 o4 = O[qt][td];
        o4[0] *= inv[qt]; o4[1] *= inv[qt]; o4[2] *= inv[qt]; o4[3] *= inv[qt];
        *(floatx4*)&sm.ep[wv][qt * 16 + l16][td * 16 + quad * 4] = o4;
    }
    __builtin_amdgcn_wave_barrier();
    {
        const int qloc = lane >> 1, half = lane & 1;
        const float* row = &sm.ep[wv][qloc][half * 32];
        u16* orow = xo + ((size_t)(b * kS + q0 + qloc)) * kHid + h * 64 + half * 32;
#pragma unroll
        for (int j = 0; j < 4; j++) {
            float4 f0 = *(const float4*)(row + j * 8);
            float4 f1 = *(const float4*)(row + j * 8 + 4);
            uint4 o;
            o.x = pk2(f0.x, f0.y); o.y = pk2(f0.z, f0.w);
            o.z = pk2(f1.x, f1.y); o.w = pk2(f1.z, f1.w);
            *(uint4*)(orow + j * 8) = o;
        }
    }
}

// ---- output projection: out = X @ Wo^T; block 128x128, wave 64x64, f32 out -
__global__ __launch_bounds__(256, 3) void oproj(const u16* __restrict__ x,
    const u16* __restrict__ w, float* __restrict__ out) {
    const int wv = threadIdx.x >> 6, lane = threadIdx.x & 63;
    const int quad = lane >> 4, l16 = lane & 15;
    const int mb = blockIdx.y * 128 + (wv >> 1) * 64;
    const int nb = blockIdx.x * 128 + (wv & 1) * 64;
    floatx4 acc[4][4] = {};
    const u16* xr = x + (size_t)(mb + l16) * kHid + quad * 8;
    const u16* wr = w + (size_t)(nb + l16) * kHid + quad * 8;
    for (int k0 = 0; k0 < kHid; k0 += 32) {
        short8 a[4], bt[4];
#pragma unroll
        for (int i = 0; i < 4; i++)
            a[i] = *(const short8*)(xr + (size_t)i * 16 * kHid + k0);
#pragma unroll
        for (int t = 0; t < 4; t++)
            bt[t] = *(const short8*)(wr + (size_t)t * 16 * kHid + k0);
#pragma unroll
        for (int i = 0; i < 4; i++)
#pragma unroll
        for (int t = 0; t < 4; t++)
            acc[i][t] = __builtin_amdgcn_mfma_f32_16x16x32_bf16(a[i], bt[t], acc[i][t], 0, 0, 0);
    }
#pragma unroll
    for (int i = 0; i < 4; i++)
#pragma unroll
    for (int t = 0; t < 4; t++)
#pragma unroll
    for (int r = 0; r < 4; r++) {
        int m = mb + i * 16 + quad * 4 + r;
        int n = nb + t * 16 + l16;
        out[(size_t)m * kHid + n] = acc[i][t][r];
    }
}

} // namespace

extern "C" void kernel_launch(void* const* d_in, const int* in_sizes, int n_in,
                              void* d_out, int out_size, void* d_ws, size_t ws_size,
                              hipStream_t stream) {
    const float* q  = (const float*)d_in[0];
    const float* k  = (const float*)d_in[1];
    const float* v  = (const float*)d_in[2];
    const int* mask = (const int*)d_in[3];
    const float* w0 = (const float*)d_in[4];
    const float* w1 = (const float*)d_in[5];
    const float* w2 = (const float*)d_in[6];
    const float* w3 = (const float*)d_in[7];
    float* out = (float*)d_out;

    // ws (u16 units): xo | wall | qp | kp | vt | fbias  (~36 MB)
    u16* ws   = (u16*)d_ws;
    u16* xo   = ws;
    u16* wall = xo + (size_t)kM * kHid;
    u16* qp   = wall + (size_t)4 * kHid * kHid;
    u16* kp   = qp + (size_t)kM * kHid;
    u16* vt   = kp + (size_t)kM * kHid;
    float* fbias = (float*)(vt + (size_t)kM * kHid);

    dim3 blk(256);
    cvt_w  <<<dim3(1024), blk, 0, stream>>>(w0, w1, w2, w3, wall);
    cvt_mask<<<dim3(kB * kS / 256), blk, 0, stream>>>(mask, fbias);
    proj_qk<<<dim3(kHid / 128, kM / 128, 2), blk, 0, stream>>>(q, k, wall, qp, kp);
    proj_v <<<dim3(kM / 128, kHid / 128), blk, 0, stream>>>(v, wall, vt);
    attn   <<<dim3(kS / 128, kBH), blk, 0, stream>>>(qp, kp, vt, fbias, xo);
    oproj  <<<dim3(kHid / 128, kM / 128), blk, 0, stream>>>(
        xo, wall + (size_t)3 * kHid * kHid, out);
}